// Round 3
// baseline (140.397 us; speedup 1.0000x reference)
//
#include <hip/hip_runtime.h>

#define E_TOTAL 800000
#define NN      50000
#define ND      64
#define ED      32
#define HD      128
#define OD      64
#define IND     160      // ED + 2*ND
#define MT      128      // edges per tile
#define NTHREADS 512
#define NT      (E_TOTAL / MT)   // 6250 tiles
#define GRID    512              // persistent blocks, 2/CU

typedef __attribute__((ext_vector_type(8))) short          short8;
typedef __attribute__((ext_vector_type(4))) float          f32x4;
typedef __attribute__((ext_vector_type(8))) unsigned short u16x8;
typedef __attribute__((ext_vector_type(4))) unsigned short u16x4;

__device__ __forceinline__ unsigned short f2bf(float f) {
  union { float f; unsigned u; } v; v.f = f;
  unsigned r = v.u + 0x7fffu + ((v.u >> 16) & 1u);   // RNE
  return (unsigned short)(r >> 16);
}

// ---------------- LDS: H (32 frags) + W1 (40 frags), frag = 1024B ----------------
// A/B frag addressing: frag_id*512 u16 + lane*8 u16 -> consecutive lanes are
// consecutive 16B -> all ds_read_b128/ds_write_b128 conflict-free.
#define H_FRAGS  32
#define SMEM_U16 ((H_FRAGS + 40) * 512)     // 36864 u16
#define SMEM_BYTES (SMEM_U16 * 2)           // 73728 B -> 2 blocks/CU

// ---------- prepass: f32 -> bf16 node table ----------
__global__ void cvt_nodes(const float* __restrict__ in, unsigned short* __restrict__ out, int n4) {
  int i = blockIdx.x * blockDim.x + threadIdx.x;
  const int stride = gridDim.x * blockDim.x;
  for (; i < n4; i += stride) {
    float4 v = ((const float4*)in)[i];
    u16x4 o = { f2bf(v.x), f2bf(v.y), f2bf(v.z), f2bf(v.w) };
    ((u16x4*)out)[i] = o;
  }
}

// ---------- prepass: pack W1 into B-fragment order ----------
__global__ void pack_w1(const float* __restrict__ w, unsigned short* __restrict__ out) {
  int i = blockIdx.x * blockDim.x + threadIdx.x;
  if (i >= HD * IND) return;
  int j = i & 7, l = (i >> 3) & 63, f = i >> 9;   // f in [0,40)
  int ks = f >> 3, t = f & 7;
  int k = ks * 32 + (l >> 4) * 8 + j;
  int n = t * 16 + (l & 15);
  out[i] = f2bf(w[k * HD + n]);
}

// ---------- prepass: pack W2 into B-fragment order ----------
__global__ void pack_w2(const float* __restrict__ w, unsigned short* __restrict__ out) {
  int i = blockIdx.x * blockDim.x + threadIdx.x;
  if (i >= OD * HD) return;
  int j = i & 7, l = (i >> 3) & 63, f = i >> 9;   // f in [0,16)
  int ks = f >> 2, t = f & 3;
  int k = ks * 32 + (l >> 4) * 8 + j;
  int n = t * 16 + (l & 15);
  out[i] = f2bf(w[k * OD + n]);
}

// ---------- main fused persistent kernel ----------
__global__ __launch_bounds__(NTHREADS, 4)
void edge_mlp(const int* __restrict__ eidx,
              const float* __restrict__ ef,
              const unsigned short* __restrict__ nbf,
              const unsigned short* __restrict__ w1p,
              const unsigned short* __restrict__ w2p,
              const float* __restrict__ b1,
              const float* __restrict__ b2,
              float* __restrict__ out)
{
  extern __shared__ unsigned short sm[];
  unsigned short* Hs = sm;                  // 32 frags (per-tile H, reused)
  unsigned short* W1 = sm + H_FRAGS * 512;  // 40 frags (staged once)

  const int tid  = threadIdx.x;
  const int wid  = tid >> 6;
  const int lane = tid & 63;
  const int lq   = lane >> 4;
  const int lr   = lane & 15;
  const int rowoff = wid * 16 + lr;         // this lane's edge-row within a tile

  // ---- stage W1 once (linear, conflict-free) ----
  #pragma unroll
  for (int c = 0; c < 5; ++c) {
    const int i = tid + c * NTHREADS;
    *(u16x8*)(W1 + i * 8) = *(const u16x8*)(w1p + i * 8);
  }

  float b1v[8];
  #pragma unroll
  for (int t = 0; t < 8; ++t) b1v[t] = b1[t * 16 + lr];
  float b2v[4];
  #pragma unroll
  for (int t = 0; t < 4; ++t) b2v[t] = b2[t * 16 + lr];

  // ---- pipeline prologue: issue tile-0 gathers straight into A-regs ----
  int tile = blockIdx.x;
  short8 g0, g1, g2, g3;      // src(k0),src(k32),tgt(k0),tgt(k32)
  float4 e0v, e1v;            // edge features f32 (cvt at use)
  {
    const long e = (long)tile * MT + rowoff;
    int si = eidx[e];           si = si < 0 ? 0 : (si >= NN ? NN - 1 : si);
    int ti = eidx[E_TOTAL + e]; ti = ti < 0 ? 0 : (ti >= NN ? NN - 1 : ti);
    const unsigned short* sr = nbf + (long)si * ND;
    const unsigned short* tr = nbf + (long)ti * ND;
    g0 = *(const short8*)(sr + lq * 8);
    g1 = *(const short8*)(sr + 32 + lq * 8);
    g2 = *(const short8*)(tr + lq * 8);
    g3 = *(const short8*)(tr + 32 + lq * 8);
    e0v = *(const float4*)(ef + e * ED + lq * 8);
    e1v = *(const float4*)(ef + e * ED + lq * 8 + 4);
  }

  // W1 visible to all waves; gathers stay in flight (lgkm-only wait)
  asm volatile("s_waitcnt lgkmcnt(0)" ::: "memory");
  __builtin_amdgcn_s_barrier();
  __builtin_amdgcn_sched_barrier(0);

  for (; tile < NT; tile += GRID) {
    // -- issue next tile's index loads early (latency hides under L1 MFMAs)
    const int  tnext = (tile + GRID < NT) ? (tile + GRID) : tile;
    const long en    = (long)tnext * MT + rowoff;
    int sn = eidx[en];
    int tn = eidx[E_TOTAL + en];

    // -- A-frag ks=0 from edge features (cvt f32->bf16)
    short8 aef;
    aef[0] = (short)f2bf(e0v.x); aef[1] = (short)f2bf(e0v.y);
    aef[2] = (short)f2bf(e0v.z); aef[3] = (short)f2bf(e0v.w);
    aef[4] = (short)f2bf(e1v.x); aef[5] = (short)f2bf(e1v.y);
    aef[6] = (short)f2bf(e1v.z); aef[7] = (short)f2bf(e1v.w);

    // -- layer 1: H[128x128] = X @ W1 (A from regs, B from LDS)
    f32x4 acc[8];
    #pragma unroll
    for (int t = 0; t < 8; ++t) acc[t] = (f32x4)0.0f;

    #pragma unroll
    for (int ks = 0; ks < 5; ++ks) {
      const short8 a = (ks == 0) ? aef : (ks == 1) ? g0 : (ks == 2) ? g1
                        : (ks == 3) ? g2 : g3;
      #pragma unroll
      for (int t = 0; t < 8; ++t) {
        const short8 b = *(const short8*)(W1 + (ks * 8 + t) * 512 + lane * 8);
        acc[t] = __builtin_amdgcn_mfma_f32_16x16x32_bf16(a, b, acc[t], 0, 0, 0);
      }
    }

    // -- barrier A: previous iteration's H readers are done
    asm volatile("s_waitcnt lgkmcnt(0)" ::: "memory");
    __builtin_amdgcn_s_barrier();
    __builtin_amdgcn_sched_barrier(0);

    // -- relu + bias -> H fragments (A-layout) in LDS
    #pragma unroll
    for (int t = 0; t < 8; ++t) {
      #pragma unroll
      for (int r = 0; r < 4; ++r) {
        float h = acc[t][r] + b1v[t];
        h = h > 0.0f ? h : 0.0f;
        const int k    = t * 16 + lr;
        const int frag = wid * 4 + (k >> 5);
        const int l2   = (((k >> 3) & 3) << 4) + lq * 4 + r;
        Hs[frag * 512 + l2 * 8 + (k & 7)] = f2bf(h);
      }
    }

    // -- barrier B: H complete
    asm volatile("s_waitcnt lgkmcnt(0)" ::: "memory");
    __builtin_amdgcn_s_barrier();
    __builtin_amdgcn_sched_barrier(0);

    // -- read this wave's H A-frags
    short8 a2[4];
    #pragma unroll
    for (int ks = 0; ks < 4; ++ks)
      a2[ks] = *(const short8*)(Hs + (wid * 4 + ks) * 512 + lane * 8);

    // -- issue next tile's gathers (idx loaded at loop top, long arrived)
    sn = sn < 0 ? 0 : (sn >= NN ? NN - 1 : sn);
    tn = tn < 0 ? 0 : (tn >= NN ? NN - 1 : tn);
    {
      const unsigned short* sr = nbf + (long)sn * ND;
      const unsigned short* tr = nbf + (long)tn * ND;
      g0 = *(const short8*)(sr + lq * 8);
      g1 = *(const short8*)(sr + 32 + lq * 8);
      g2 = *(const short8*)(tr + lq * 8);
      g3 = *(const short8*)(tr + 32 + lq * 8);
      e0v = *(const float4*)(ef + en * ED + lq * 8);
      e1v = *(const float4*)(ef + en * ED + lq * 8 + 4);
    }

    // -- layer 2: OUT[128x64] = H @ W2 (B from global, L1/L2-hot)
    f32x4 acc2[4];
    #pragma unroll
    for (int t = 0; t < 4; ++t) acc2[t] = (f32x4)0.0f;
    #pragma unroll
    for (int t = 0; t < 4; ++t) {
      #pragma unroll
      for (int ks = 0; ks < 4; ++ks) {
        const short8 b = *(const short8*)(w2p + ((ks * 4 + t) * 64 + lane) * 8);
        acc2[t] = __builtin_amdgcn_mfma_f32_16x16x32_bf16(a2[ks], b, acc2[t], 0, 0, 0);
      }
    }

    // -- epilogue: bias + f32 store
    const long mbase = (long)tile * MT + wid * 16 + lq * 4;
    #pragma unroll
    for (int t = 0; t < 4; ++t) {
      #pragma unroll
      for (int r = 0; r < 4; ++r) {
        out[(mbase + r) * OD + t * 16 + lr] = acc2[t][r] + b2v[t];
      }
    }
  }
}

extern "C" void kernel_launch(void* const* d_in, const int* in_sizes, int n_in,
                              void* d_out, int out_size, void* d_ws, size_t ws_size,
                              hipStream_t stream) {
  const int*   eidx = (const int*)d_in[0];      // (2, E) int32
  const float* nf   = (const float*)d_in[1];    // (NN, 64)
  const float* ef   = (const float*)d_in[2];    // (E, 32)
  const float* w1   = (const float*)d_in[3];    // (160, 128)
  const float* b1   = (const float*)d_in[4];    // (128,)
  const float* w2   = (const float*)d_in[5];    // (128, 64)
  const float* b2   = (const float*)d_in[6];    // (64,)
  float*       out  = (float*)d_out;            // (E, 64)

  unsigned short* nbf = (unsigned short*)d_ws;            // NN*ND
  unsigned short* w1p = nbf + (long)NN * ND;              // HD*IND
  unsigned short* w2p = w1p + (long)HD * IND;             // OD*HD

  cvt_nodes<<<1024, 256, 0, stream>>>(nf, nbf, (NN * ND) / 4);
  pack_w1<<<(HD * IND + 255) / 256, 256, 0, stream>>>(w1, w1p);
  pack_w2<<<(OD * HD + 255) / 256, 256, 0, stream>>>(w2, w2p);

  hipFuncSetAttribute((const void*)edge_mlp,
                      hipFuncAttributeMaxDynamicSharedMemorySize, SMEM_BYTES);
  edge_mlp<<<GRID, NTHREADS, SMEM_BYTES, stream>>>(
      eidx, ef, nbf, w1p, w2p, b1, b2, out);
}